// Round 2
// baseline (1629.077 us; speedup 1.0000x reference)
//
#include <hip/hip_runtime.h>
#include <hip/hip_bf16.h>

#define NPIX   65536
#define BATCH  2
#define TT     5
#define CC     10
#define HH     32
#define WIDTH  64
#define KW     32
#define OUTC   10

// ---- workspace layout (float offsets) ----
#define OFF_W0IH 0          // 1280
#define OFF_W0HH 1280       // 4096
#define OFF_BC0  5376       // 128
#define OFF_W1IH 5504       // 4096
#define OFF_W1HH 9600       // 4096
#define OFF_BC1  13696      // 128
#define OFF_FC1W 13824      // 2048
#define OFF_FC1B 15872      // 64
#define OFF_CWT  15936      // 16384  conv_w transposed [k][co][ci]
#define OFF_CB   32320      // 256
#define OFF_FC2W 32576      // 2048
#define OFF_FC2B 34624      // 32
#define OFF_FC3W 34656      // 320
#define OFF_FC3B 34976      // 10
#define OFF_FEATS 36864     // 8388608
#define OFF_Y    (36864 + 8388608)

// straight-distance edge: first edge of block (di=-1,dj=0) at row 255*255=65025
#define STRAIGHT_ATTR_IDX (65025 * 3)

__device__ __forceinline__ float sigf(float x)  { return 1.0f / (1.0f + __expf(-x)); }
__device__ __forceinline__ float tanhf_(float x){ return 1.0f - 2.0f / (__expf(2.0f * x) + 1.0f); }

// ---------------- prep: params -> fp32 ws (combine biases, transpose conv_w) ----------------
__global__ void prep_kernel(const float* Wih0, const float* Whh0,
                            const float* bih0, const float* bhh0,
                            const float* Wih1, const float* Whh1,
                            const float* bih1, const float* bhh1,
                            const float* fc1w, const float* fc1b,
                            const float* convw, const float* convb,
                            const float* fc2w, const float* fc2b,
                            const float* fc3w, const float* fc3b,
                            float* P) {
    int tid = blockIdx.x * blockDim.x + threadIdx.x;
    int stride = gridDim.x * blockDim.x;
    for (int i = tid; i < 1280; i += stride) P[OFF_W0IH + i] = Wih0[i];
    for (int i = tid; i < 4096; i += stride) P[OFF_W0HH + i] = Whh0[i];
    for (int i = tid; i < 128;  i += stride) P[OFF_BC0 + i]  = bih0[i] + bhh0[i];
    for (int i = tid; i < 4096; i += stride) P[OFF_W1IH + i] = Wih1[i];
    for (int i = tid; i < 4096; i += stride) P[OFF_W1HH + i] = Whh1[i];
    for (int i = tid; i < 128;  i += stride) P[OFF_BC1 + i]  = bih1[i] + bhh1[i];
    for (int i = tid; i < 2048; i += stride) P[OFF_FC1W + i] = fc1w[i];
    for (int i = tid; i < 64;   i += stride) P[OFF_FC1B + i] = fc1b[i];
    // conv_w[k][ci][co] -> cwT[k][co][ci]
    for (int i = tid; i < 16384; i += stride) {
        int k = i >> 12, r = i & 4095, ci = r >> 6, co = r & 63;
        P[OFF_CWT + (k << 12) + co * 64 + ci] = convw[i];
    }
    for (int i = tid; i < 256;  i += stride) P[OFF_CB + i]   = convb[i];
    for (int i = tid; i < 2048; i += stride) P[OFF_FC2W + i] = fc2w[i];
    for (int i = tid; i < 32;   i += stride) P[OFF_FC2B + i] = fc2b[i];
    for (int i = tid; i < 320;  i += stride) P[OFF_FC3W + i] = fc3w[i];
    for (int i = tid; i < 10;   i += stride) P[OFF_FC3B + i] = fc3b[i];
}

// ---------------- LSTM (2 layers, T=5) + fc1, one thread per node ----------------
__global__ __launch_bounds__(256, 1)
void lstm_fc1_kernel(const float* __restrict__ x,
                     const float* __restrict__ P,
                     float* __restrict__ feats) {
    int n = blockIdx.x * 256 + threadIdx.x;
    int b = n >> 16;
    int pix = n & (NPIX - 1);
    const float* xb = x + (size_t)b * TT * CC * NPIX + pix;

    float h0[HH], c0[HH], h1[HH], c1[HH];
#pragma unroll
    for (int j = 0; j < HH; j++) { h0[j] = 0.f; c0[j] = 0.f; h1[j] = 0.f; c1[j] = 0.f; }

    for (int t = 0; t < TT; t++) {
        float xt[CC];
#pragma unroll
        for (int c = 0; c < CC; c++) xt[c] = xb[(size_t)(t * CC + c) * NPIX];

        float hn[HH];
        // ---- layer 0 ----
#pragma unroll
        for (int j = 0; j < HH; j++) {
            float zi = P[OFF_BC0 + j];
            float zf = P[OFF_BC0 + HH + j];
            float zg = P[OFF_BC0 + 2 * HH + j];
            float zo = P[OFF_BC0 + 3 * HH + j];
#pragma unroll
            for (int c = 0; c < CC; c++) {
                float xv = xt[c];
                zi += P[OFF_W0IH + j * CC + c] * xv;
                zf += P[OFF_W0IH + (HH + j) * CC + c] * xv;
                zg += P[OFF_W0IH + (2 * HH + j) * CC + c] * xv;
                zo += P[OFF_W0IH + (3 * HH + j) * CC + c] * xv;
            }
#pragma unroll
            for (int k = 0; k < HH; k++) {
                float hv = h0[k];
                zi += P[OFF_W0HH + j * HH + k] * hv;
                zf += P[OFF_W0HH + (HH + j) * HH + k] * hv;
                zg += P[OFF_W0HH + (2 * HH + j) * HH + k] * hv;
                zo += P[OFF_W0HH + (3 * HH + j) * HH + k] * hv;
            }
            float cn = sigf(zf) * c0[j] + sigf(zi) * tanhf_(zg);
            c0[j] = cn;
            hn[j] = sigf(zo) * tanhf_(cn);
        }
#pragma unroll
        for (int j = 0; j < HH; j++) h0[j] = hn[j];

        // ---- layer 1 (input = new h0) ----
#pragma unroll
        for (int j = 0; j < HH; j++) {
            float zi = P[OFF_BC1 + j];
            float zf = P[OFF_BC1 + HH + j];
            float zg = P[OFF_BC1 + 2 * HH + j];
            float zo = P[OFF_BC1 + 3 * HH + j];
#pragma unroll
            for (int k = 0; k < HH; k++) {
                float hv = h0[k];
                zi += P[OFF_W1IH + j * HH + k] * hv;
                zf += P[OFF_W1IH + (HH + j) * HH + k] * hv;
                zg += P[OFF_W1IH + (2 * HH + j) * HH + k] * hv;
                zo += P[OFF_W1IH + (3 * HH + j) * HH + k] * hv;
            }
#pragma unroll
            for (int k = 0; k < HH; k++) {
                float hv = h1[k];
                zi += P[OFF_W1HH + j * HH + k] * hv;
                zf += P[OFF_W1HH + (HH + j) * HH + k] * hv;
                zg += P[OFF_W1HH + (2 * HH + j) * HH + k] * hv;
                zo += P[OFF_W1HH + (3 * HH + j) * HH + k] * hv;
            }
            float cn = sigf(zf) * c1[j] + sigf(zi) * tanhf_(zg);
            c1[j] = cn;
            hn[j] = sigf(zo) * tanhf_(cn);
        }
#pragma unroll
        for (int j = 0; j < HH; j++) h1[j] = hn[j];
    }

    // ---- fc1 + relu, store planar feats[b][ch][pix] ----
    float* fb = feats + (size_t)b * WIDTH * NPIX + pix;
    for (int ch = 0; ch < WIDTH; ch++) {
        float a = P[OFF_FC1B + ch];
#pragma unroll
        for (int k = 0; k < HH; k++) a += P[OFF_FC1W + ch * HH + k] * h1[k];
        fb[(size_t)ch * NPIX] = fmaxf(a, 0.f);
    }
}

// ---------------- per-layer matmul: Y = feats @ conv_w[k] ----------------
__global__ __launch_bounds__(256, 2)
void feats_mm_kernel(const float* __restrict__ feats, const float* __restrict__ P,
                     float* __restrict__ Y, int k) {
    int n = blockIdx.x * 256 + threadIdx.x;
    int b = n >> 16;
    int pix = n & (NPIX - 1);
    const float* fb = feats + (size_t)b * WIDTH * NPIX + pix;
    float fin[WIDTH];
#pragma unroll
    for (int ci = 0; ci < WIDTH; ci++) fin[ci] = fb[(size_t)ci * NPIX];
    float* yb = Y + (size_t)b * WIDTH * NPIX + pix;
    const float* w = P + OFF_CWT + (k << 12);
    for (int co = 0; co < WIDTH; co++) {
        float acc = 0.f;
#pragma unroll
        for (int ci = 0; ci < WIDTH; ci++) acc += w[co * WIDTH + ci] * fin[ci];
        yb[(size_t)co * NPIX] = acc;
    }
}

__device__ __forceinline__ void gauss_weights(const float* gparam,
                                              const float* eattr,
                                              int k, float& wstr, float& wdiag) {
    float g = gparam[k];
    float denom = g * g + 1e-8f;
    float as = eattr[STRAIGHT_ATTR_IDX]; // 1.0
    float ad = eattr[0];                 // f32(sqrt(2))
    wstr  = __expf(-(as * as) / denom);
    wdiag = __expf(-(ad * ad) / denom);
}

// ---------------- stencil: feats = gather-stencil(Y) + Y + b, relu ----------------
__global__ __launch_bounds__(256, 2)
void conv_stencil_kernel(const float* __restrict__ Y, const float* __restrict__ P,
                         const float* __restrict__ gparam,
                         const float* __restrict__ eattr,
                         float* __restrict__ feats, int k) {
    int n = blockIdx.x * 256 + threadIdx.x;
    int b = n >> 16;
    int pix = n & (NPIX - 1);
    int i = pix >> 8, j = pix & 255;
    float wstr, wdiag;
    gauss_weights(gparam, eattr, k, wstr, wdiag);
    bool up = i > 0, dn = i < 255, lf = j > 0, rt = j < 255;
    const float* yb = Y + (size_t)b * WIDTH * NPIX + pix;
    float* fb = feats + (size_t)b * WIDTH * NPIX + pix;
    const float* cb = P + OFF_CB + k * WIDTH;
    for (int ch = 0; ch < WIDTH; ch++) {
        const float* yc = yb + (size_t)ch * NPIX;
        float ctr = yc[0];
        float ss = 0.f, sd = 0.f;
        if (up) ss += yc[-256];
        if (dn) ss += yc[256];
        if (lf) ss += yc[-1];
        if (rt) ss += yc[1];
        if (up && lf) sd += yc[-257];
        if (up && rt) sd += yc[-255];
        if (dn && lf) sd += yc[255];
        if (dn && rt) sd += yc[257];
        float v = ss * wstr + sd * wdiag + ctr + cb[ch];
        fb[(size_t)ch * NPIX] = fmaxf(v, 0.f);
    }
}

// ---------------- last layer stencil (no relu) fused with fc2/fc3 head ----------------
__global__ __launch_bounds__(256, 1)
void conv_head_kernel(const float* __restrict__ Y, const float* __restrict__ P,
                      const float* __restrict__ gparam,
                      const float* __restrict__ eattr,
                      float* __restrict__ out) {
    const int k = 3;
    int n = blockIdx.x * 256 + threadIdx.x;
    int b = n >> 16;
    int pix = n & (NPIX - 1);
    int i = pix >> 8, j = pix & 255;
    float wstr, wdiag;
    gauss_weights(gparam, eattr, k, wstr, wdiag);
    bool up = i > 0, dn = i < 255, lf = j > 0, rt = j < 255;
    const float* yb = Y + (size_t)b * WIDTH * NPIX + pix;
    const float* cb = P + OFF_CB + k * WIDTH;

    float f[WIDTH];
#pragma unroll
    for (int ch = 0; ch < WIDTH; ch++) {
        const float* yc = yb + (size_t)ch * NPIX;
        float ctr = yc[0];
        float ss = 0.f, sd = 0.f;
        if (up) ss += yc[-256];
        if (dn) ss += yc[256];
        if (lf) ss += yc[-1];
        if (rt) ss += yc[1];
        if (up && lf) sd += yc[-257];
        if (up && rt) sd += yc[-255];
        if (dn && lf) sd += yc[255];
        if (dn && rt) sd += yc[257];
        f[ch] = ss * wstr + sd * wdiag + ctr + cb[ch];   // k==3: no relu
    }

    float t2[KW];
#pragma unroll
    for (int m = 0; m < KW; m++) {
        float a = P[OFF_FC2B + m];
#pragma unroll
        for (int ch = 0; ch < WIDTH; ch++) a += P[OFF_FC2W + m * WIDTH + ch] * f[ch];
        t2[m] = fmaxf(a, 0.f);
    }
    float* ob = out + (size_t)b * OUTC * NPIX + pix;
    for (int oc = 0; oc < OUTC; oc++) {
        float a = P[OFF_FC3B + oc];
#pragma unroll
        for (int m = 0; m < KW; m++) a += P[OFF_FC3W + oc * KW + m] * t2[m];
        ob[(size_t)oc * NPIX] = a;
    }
}

extern "C" void kernel_launch(void* const* d_in, const int* in_sizes, int n_in,
                              void* d_out, int out_size, void* d_ws, size_t ws_size,
                              hipStream_t stream) {
    const float* x     = (const float*)d_in[0];
    const float* eattr = (const float*)d_in[3];
    const float* Wih0  = (const float*)d_in[4];
    const float* Whh0  = (const float*)d_in[5];
    const float* bih0  = (const float*)d_in[6];
    const float* bhh0  = (const float*)d_in[7];
    const float* Wih1  = (const float*)d_in[8];
    const float* Whh1  = (const float*)d_in[9];
    const float* bih1  = (const float*)d_in[10];
    const float* bhh1  = (const float*)d_in[11];
    const float* fc1w  = (const float*)d_in[12];
    const float* fc1b  = (const float*)d_in[13];
    const float* convw = (const float*)d_in[14];
    const float* convb = (const float*)d_in[15];
    const float* gparam= (const float*)d_in[16];
    const float* fc2w  = (const float*)d_in[17];
    const float* fc2b  = (const float*)d_in[18];
    const float* fc3w  = (const float*)d_in[19];
    const float* fc3b  = (const float*)d_in[20];

    float* P     = (float*)d_ws;
    float* feats = P + OFF_FEATS;
    float* Y     = P + OFF_Y;

    prep_kernel<<<64, 256, 0, stream>>>(Wih0, Whh0, bih0, bhh0, Wih1, Whh1, bih1, bhh1,
                                        fc1w, fc1b, convw, convb, fc2w, fc2b, fc3w, fc3b, P);
    lstm_fc1_kernel<<<512, 256, 0, stream>>>(x, P, feats);
    for (int k = 0; k < 4; k++) {
        feats_mm_kernel<<<512, 256, 0, stream>>>(feats, P, Y, k);
        if (k < 3)
            conv_stencil_kernel<<<512, 256, 0, stream>>>(Y, P, gparam, eattr, feats, k);
        else
            conv_head_kernel<<<512, 256, 0, stream>>>(Y, P, gparam, eattr,
                                                      (float*)d_out);
    }
}

// Round 3
// 1577.537 us; speedup vs baseline: 1.0327x; 1.0327x over previous
//
#include <hip/hip_runtime.h>
#include <hip/hip_bf16.h>

#define NPIX   65536
#define TT     5
#define CC     10
#define HH     32
#define WIDTH  64
#define KW     32
#define OUTC   10

// ---- workspace layout (float offsets) ----
// LSTM gate-pair packed weights: pairs (i,f) and (g,o); stored as float2 (2 floats)
#define OFF_PB0IF   0        // 64  (32 float2)
#define OFF_PB0GO   64       // 64
#define OFF_PB1IF   128      // 64
#define OFF_PB1GO   192      // 64
#define OFF_PW0I_IF 256      // 640  [j][c] float2
#define OFF_PW0I_GO 896      // 640
#define OFF_PW0H_IF 1536     // 2048 [j][k] float2
#define OFF_PW0H_GO 3584     // 2048
#define OFF_PW1I_IF 5632     // 2048
#define OFF_PW1I_GO 7680     // 2048
#define OFF_PW1H_IF 9728     // 2048
#define OFF_PW1H_GO 11776    // 2048
#define OFF_FC1W    13824    // 2048 [ch2][k] float2 (channel pairs)
#define OFF_FC1B    15872    // 64
#define OFF_CWT2    16384    // 16384 [k][co2][ci] float2
#define OFF_CB      32768    // 256
#define OFF_FC2W2   33024    // 2048 [m2][ch] float2
#define OFF_FC2B    35072    // 32
#define OFF_FC3W2   35104    // 320 [oc2][m] float2
#define OFF_FC3B    35424    // 16
#define OFF_GW      35440    // 8  (wstr,wdiag per k)
#define OFF_FEATS_A 65536            // 8388608
#define OFF_FEATS_B (65536 + 8388608)

#define STRAIGHT_ATTR_IDX (65025 * 3)

__device__ __forceinline__ float sigf(float x)  { return 1.0f / (1.0f + __expf(-x)); }
__device__ __forceinline__ float tanhf_(float x){ return 1.0f - 2.0f / (__expf(2.0f * x) + 1.0f); }

// ---------------- prep: pack/transpose all params into fp32 ws ----------------
__global__ void prep_kernel(const float* Wih0, const float* Whh0,
                            const float* bih0, const float* bhh0,
                            const float* Wih1, const float* Whh1,
                            const float* bih1, const float* bhh1,
                            const float* fc1w, const float* fc1b,
                            const float* convw, const float* convb,
                            const float* fc2w, const float* fc2b,
                            const float* fc3w, const float* fc3b,
                            const float* gparam, const float* eattr,
                            float* P) {
    int tid = blockIdx.x * blockDim.x + threadIdx.x;
    int stride = gridDim.x * blockDim.x;
    // biases: pair (i,f) -> gates 0,1 ; (g,o) -> gates 2,3
    for (int i = tid; i < 64; i += stride) {
        int j = i >> 1, h = i & 1;
        P[OFF_PB0IF + i] = bih0[h * 32 + j] + bhh0[h * 32 + j];
        P[OFF_PB0GO + i] = bih0[(2 + h) * 32 + j] + bhh0[(2 + h) * 32 + j];
        P[OFF_PB1IF + i] = bih1[h * 32 + j] + bhh1[h * 32 + j];
        P[OFF_PB1GO + i] = bih1[(2 + h) * 32 + j] + bhh1[(2 + h) * 32 + j];
    }
    for (int idx = tid; idx < 640; idx += stride) {
        int e = idx >> 1, h = idx & 1, j = e / 10, c = e % 10;
        P[OFF_PW0I_IF + idx] = Wih0[(h * 32 + j) * 10 + c];
        P[OFF_PW0I_GO + idx] = Wih0[((2 + h) * 32 + j) * 10 + c];
    }
    for (int idx = tid; idx < 2048; idx += stride) {
        int e = idx >> 1, h = idx & 1, j = e >> 5, k = e & 31;
        P[OFF_PW0H_IF + idx] = Whh0[(h * 32 + j) * 32 + k];
        P[OFF_PW0H_GO + idx] = Whh0[((2 + h) * 32 + j) * 32 + k];
        P[OFF_PW1I_IF + idx] = Wih1[(h * 32 + j) * 32 + k];
        P[OFF_PW1I_GO + idx] = Wih1[((2 + h) * 32 + j) * 32 + k];
        P[OFF_PW1H_IF + idx] = Whh1[(h * 32 + j) * 32 + k];
        P[OFF_PW1H_GO + idx] = Whh1[((2 + h) * 32 + j) * 32 + k];
        // fc1 channel-pair pack: [ch2][k] -> (w[2ch2][k], w[2ch2+1][k])
        int ch2 = e >> 5, kk = e & 31;
        P[OFF_FC1W + idx] = fc1w[(2 * ch2 + h) * 32 + kk];
        // fc2 pack [m2][ch]
        int m2 = e >> 6, ch = e & 63;
        P[OFF_FC2W2 + idx] = fc2w[(2 * m2 + h) * 64 + ch];
    }
    for (int i = tid; i < 64; i += stride) P[OFF_FC1B + i] = fc1b[i];
    // conv_w[k][ci][co] -> [k][co2][ci] float2
    for (int idx = tid; idx < 16384; idx += stride) {
        int k = idx >> 12, r = idx & 4095, e = r >> 1, h = r & 1;
        int co2 = e >> 6, ci = e & 63;
        P[OFF_CWT2 + idx] = convw[k * 4096 + ci * 64 + (2 * co2 + h)];
    }
    for (int i = tid; i < 256; i += stride) P[OFF_CB + i] = convb[i];
    for (int i = tid; i < 32;  i += stride) P[OFF_FC2B + i] = fc2b[i];
    for (int idx = tid; idx < 320; idx += stride) {
        int e = idx >> 1, h = idx & 1, oc2 = e >> 5, m = e & 31;
        P[OFF_FC3W2 + idx] = fc3w[(2 * oc2 + h) * 32 + m];
    }
    for (int i = tid; i < 10; i += stride) P[OFF_FC3B + i] = fc3b[i];
    for (int idx = tid; idx < 8; idx += stride) {
        int k = idx >> 1;
        float g = gparam[k];
        float denom = g * g + 1e-8f;
        float a = (idx & 1) ? eattr[0] : eattr[STRAIGHT_ATTR_IDX];
        P[OFF_GW + idx] = __expf(-(a * a) / denom);
    }
}

// ---------------- LSTM: 4 waves/pixel-group; wave w owns hidden units [8w,8w+8) ----------------
__global__ __launch_bounds__(256, 4)
void lstm_fc1_kernel(const float* __restrict__ x,
                     const float* __restrict__ P,
                     float* __restrict__ feats) {
    __shared__ float hx0[64 * 36];
    __shared__ float hx1[64 * 36];
    int p = threadIdx.x & 63;
    int subj = __builtin_amdgcn_readfirstlane(threadIdx.x >> 6); // wave-uniform SGPR
    int n = blockIdx.x * 64 + p;
    int b = n >> 16;
    int pix = n & (NPIX - 1);
    const float* xb = x + (size_t)b * TT * CC * NPIX + pix;

    const float2* W0Iif = (const float2*)(P + OFF_PW0I_IF);
    const float2* W0Igo = (const float2*)(P + OFF_PW0I_GO);
    const float2* W0Hif = (const float2*)(P + OFF_PW0H_IF);
    const float2* W0Hgo = (const float2*)(P + OFF_PW0H_GO);
    const float2* W1Iif = (const float2*)(P + OFF_PW1I_IF);
    const float2* W1Igo = (const float2*)(P + OFF_PW1I_GO);
    const float2* W1Hif = (const float2*)(P + OFF_PW1H_IF);
    const float2* W1Hgo = (const float2*)(P + OFF_PW1H_GO);
    const float2* B0if  = (const float2*)(P + OFF_PB0IF);
    const float2* B0go  = (const float2*)(P + OFF_PB0GO);
    const float2* B1if  = (const float2*)(P + OFF_PB1IF);
    const float2* B1go  = (const float2*)(P + OFF_PB1GO);

    float h0a[32], h1a[32], c0[8], c1[8];
#pragma unroll
    for (int k = 0; k < 32; k++) { h0a[k] = 0.f; h1a[k] = 0.f; }
#pragma unroll
    for (int k = 0; k < 8; k++) { c0[k] = 0.f; c1[k] = 0.f; }

    int ldsbase = p * 36;
    int myoff = ldsbase + subj * 8;

#pragma unroll 1
    for (int t = 0; t < TT; t++) {
        float xt[CC];
#pragma unroll
        for (int c = 0; c < CC; c++) xt[c] = xb[(size_t)(t * CC + c) * NPIX];

        // ---- layer 0: my 8 hidden units ----
#pragma unroll
        for (int jj = 0; jj < 8; jj++) {
            int j = subj * 8 + jj;
            float2 zif = B0if[j];
            float2 zgo = B0go[j];
            const float2* wi_if = W0Iif + j * CC;
            const float2* wi_go = W0Igo + j * CC;
#pragma unroll
            for (int c = 0; c < CC; c++) {
                float xv = xt[c];
                float2 a = wi_if[c], g = wi_go[c];
                zif.x += a.x * xv; zif.y += a.y * xv;
                zgo.x += g.x * xv; zgo.y += g.y * xv;
            }
            const float2* wh_if = W0Hif + j * HH;
            const float2* wh_go = W0Hgo + j * HH;
#pragma unroll
            for (int k = 0; k < HH; k++) {
                float hv = h0a[k];
                float2 a = wh_if[k], g = wh_go[k];
                zif.x += a.x * hv; zif.y += a.y * hv;
                zgo.x += g.x * hv; zgo.y += g.y * hv;
            }
            float cn = sigf(zif.y) * c0[jj] + sigf(zif.x) * tanhf_(zgo.x);
            c0[jj] = cn;
            hx0[myoff + jj] = sigf(zgo.y) * tanhf_(cn);
        }
        __syncthreads();
#pragma unroll
        for (int k = 0; k < HH; k++) h0a[k] = hx0[ldsbase + k];

        // ---- layer 1 ----
#pragma unroll
        for (int jj = 0; jj < 8; jj++) {
            int j = subj * 8 + jj;
            float2 zif = B1if[j];
            float2 zgo = B1go[j];
            const float2* wi_if = W1Iif + j * HH;
            const float2* wi_go = W1Igo + j * HH;
            const float2* wh_if = W1Hif + j * HH;
            const float2* wh_go = W1Hgo + j * HH;
#pragma unroll
            for (int k = 0; k < HH; k++) {
                float hv = h0a[k];
                float2 a = wi_if[k], g = wi_go[k];
                zif.x += a.x * hv; zif.y += a.y * hv;
                zgo.x += g.x * hv; zgo.y += g.y * hv;
            }
#pragma unroll
            for (int k = 0; k < HH; k++) {
                float hv = h1a[k];
                float2 a = wh_if[k], g = wh_go[k];
                zif.x += a.x * hv; zif.y += a.y * hv;
                zgo.x += g.x * hv; zgo.y += g.y * hv;
            }
            float cn = sigf(zif.y) * c1[jj] + sigf(zif.x) * tanhf_(zgo.x);
            c1[jj] = cn;
            hx1[myoff + jj] = sigf(zgo.y) * tanhf_(cn);
        }
        __syncthreads();
#pragma unroll
        for (int k = 0; k < HH; k++) h1a[k] = hx1[ldsbase + k];
    }

    // ---- fc1 + relu: my 16 channels (8 pairs) ----
    const float2* F1 = (const float2*)(P + OFF_FC1W);
    float* fb = feats + (size_t)b * WIDTH * NPIX + pix;
#pragma unroll
    for (int cc = 0; cc < 8; cc++) {
        int ch2 = subj * 8 + cc;
        float ax = P[OFF_FC1B + 2 * ch2];
        float ay = P[OFF_FC1B + 2 * ch2 + 1];
        const float2* w = F1 + ch2 * HH;
#pragma unroll
        for (int k = 0; k < HH; k++) {
            float hv = h1a[k];
            float2 ww = w[k];
            ax += ww.x * hv; ay += ww.y * hv;
        }
        fb[(size_t)(2 * ch2) * NPIX]     = fmaxf(ax, 0.f);
        fb[(size_t)(2 * ch2 + 1) * NPIX] = fmaxf(ay, 0.f);
    }
}

// ---------------- fused conv layer: u = stencil(Fin); Fout = relu(u @ W[k] + b[k]) ----------------
__global__ __launch_bounds__(256, 4)
void conv_fused_kernel(const float* __restrict__ Fin, float* __restrict__ Fout,
                       const float* __restrict__ P, int k) {
    int n = blockIdx.x * 256 + threadIdx.x;
    int b = n >> 16;
    int pix = n & (NPIX - 1);
    int i = pix >> 8, j = pix & 255;
    float wstr = P[OFF_GW + 2 * k], wdiag = P[OFF_GW + 2 * k + 1];
    int oU = (i > 0)   ? -256 : 0;
    int oD = (i < 255) ?  256 : 0;
    int oL = (j > 0)   ?   -1 : 0;
    int oR = (j < 255) ?    1 : 0;
    float fu = (i > 0) ? 1.f : 0.f, fd = (i < 255) ? 1.f : 0.f;
    float fl = (j > 0) ? 1.f : 0.f, fr = (j < 255) ? 1.f : 0.f;
    float ful = fu * fl, fur = fu * fr, fdl = fd * fl, fdr = fd * fr;

    const float* fb = Fin + (size_t)b * WIDTH * NPIX + pix;
    float u[WIDTH];
#pragma unroll
    for (int ch = 0; ch < WIDTH; ch++) {
        const float* yc = fb + (size_t)ch * NPIX;
        float ss = fu * yc[oU] + fd * yc[oD] + fl * yc[oL] + fr * yc[oR];
        float sd = ful * yc[oU + oL] + fur * yc[oU + oR]
                 + fdl * yc[oD + oL] + fdr * yc[oD + oR];
        u[ch] = yc[0] + wstr * ss + wdiag * sd;
    }

    const float2* w2 = (const float2*)(P + OFF_CWT2 + k * 4096);
    const float*  cb = P + OFF_CB + k * WIDTH;
    float* ob = Fout + (size_t)b * WIDTH * NPIX + pix;
    for (int co2 = 0; co2 < 32; co2++) {
        float ax = cb[2 * co2], ay = cb[2 * co2 + 1];
        const float2* w = w2 + co2 * WIDTH;
#pragma unroll
        for (int ci = 0; ci < WIDTH; ci++) {
            float uv = u[ci];
            float2 ww = w[ci];
            ax += ww.x * uv; ay += ww.y * uv;
        }
        ob[(size_t)(2 * co2) * NPIX]     = fmaxf(ax, 0.f);
        ob[(size_t)(2 * co2 + 1) * NPIX] = fmaxf(ay, 0.f);
    }
}

// ---------------- last conv (no relu) + fc2/fc3 head ----------------
__global__ __launch_bounds__(256, 3)
void conv_head_kernel(const float* __restrict__ Fin, const float* __restrict__ P,
                      float* __restrict__ out) {
    const int k = 3;
    int n = blockIdx.x * 256 + threadIdx.x;
    int b = n >> 16;
    int pix = n & (NPIX - 1);
    int i = pix >> 8, j = pix & 255;
    float wstr = P[OFF_GW + 2 * k], wdiag = P[OFF_GW + 2 * k + 1];
    int oU = (i > 0)   ? -256 : 0;
    int oD = (i < 255) ?  256 : 0;
    int oL = (j > 0)   ?   -1 : 0;
    int oR = (j < 255) ?    1 : 0;
    float fu = (i > 0) ? 1.f : 0.f, fd = (i < 255) ? 1.f : 0.f;
    float fl = (j > 0) ? 1.f : 0.f, fr = (j < 255) ? 1.f : 0.f;
    float ful = fu * fl, fur = fu * fr, fdl = fd * fl, fdr = fd * fr;

    const float* fb = Fin + (size_t)b * WIDTH * NPIX + pix;
    float u[WIDTH];
#pragma unroll
    for (int ch = 0; ch < WIDTH; ch++) {
        const float* yc = fb + (size_t)ch * NPIX;
        float ss = fu * yc[oU] + fd * yc[oD] + fl * yc[oL] + fr * yc[oR];
        float sd = ful * yc[oU + oL] + fur * yc[oU + oR]
                 + fdl * yc[oD + oL] + fdr * yc[oD + oR];
        u[ch] = yc[0] + wstr * ss + wdiag * sd;
    }

    // f = u @ W[3] + b[3]  (no relu)
    const float2* w2 = (const float2*)(P + OFF_CWT2 + k * 4096);
    const float*  cb = P + OFF_CB + k * WIDTH;
    float f[WIDTH];
#pragma unroll
    for (int co2 = 0; co2 < 32; co2++) {
        float ax = cb[2 * co2], ay = cb[2 * co2 + 1];
        const float2* w = w2 + co2 * WIDTH;
#pragma unroll
        for (int ci = 0; ci < WIDTH; ci++) {
            float uv = u[ci];
            float2 ww = w[ci];
            ax += ww.x * uv; ay += ww.y * uv;
        }
        f[2 * co2] = ax; f[2 * co2 + 1] = ay;
    }

    // out accumulation: o[oc] = fc3b[oc] + sum_m fc3w[oc][m] * relu(fc2(f))[m]
    float o[OUTC];
#pragma unroll
    for (int oc = 0; oc < OUTC; oc++) o[oc] = P[OFF_FC3B + oc];
    const float2* F2 = (const float2*)(P + OFF_FC2W2);
    for (int m2 = 0; m2 < 16; m2++) {
        float ax = P[OFF_FC2B + 2 * m2], ay = P[OFF_FC2B + 2 * m2 + 1];
        const float2* w = F2 + m2 * WIDTH;
#pragma unroll
        for (int ch = 0; ch < WIDTH; ch++) {
            float fv = f[ch];
            float2 ww = w[ch];
            ax += ww.x * fv; ay += ww.y * fv;
        }
        ax = fmaxf(ax, 0.f); ay = fmaxf(ay, 0.f);
#pragma unroll
        for (int oc = 0; oc < OUTC; oc++) {
            // fc3 packed [oc2][m]: element (oc, m) at OFF_FC3W2 + (oc>>1)*64 + m*2 + (oc&1)
            o[oc] += P[OFF_FC3W2 + (oc >> 1) * 64 + (2 * m2) * 2 + (oc & 1)] * ax
                   + P[OFF_FC3W2 + (oc >> 1) * 64 + (2 * m2 + 1) * 2 + (oc & 1)] * ay;
        }
    }
    float* ob = out + (size_t)b * OUTC * NPIX + pix;
#pragma unroll
    for (int oc = 0; oc < OUTC; oc++) ob[(size_t)oc * NPIX] = o[oc];
}

extern "C" void kernel_launch(void* const* d_in, const int* in_sizes, int n_in,
                              void* d_out, int out_size, void* d_ws, size_t ws_size,
                              hipStream_t stream) {
    const float* x     = (const float*)d_in[0];
    const float* eattr = (const float*)d_in[3];
    const float* Wih0  = (const float*)d_in[4];
    const float* Whh0  = (const float*)d_in[5];
    const float* bih0  = (const float*)d_in[6];
    const float* bhh0  = (const float*)d_in[7];
    const float* Wih1  = (const float*)d_in[8];
    const float* Whh1  = (const float*)d_in[9];
    const float* bih1  = (const float*)d_in[10];
    const float* bhh1  = (const float*)d_in[11];
    const float* fc1w  = (const float*)d_in[12];
    const float* fc1b  = (const float*)d_in[13];
    const float* convw = (const float*)d_in[14];
    const float* convb = (const float*)d_in[15];
    const float* gparam= (const float*)d_in[16];
    const float* fc2w  = (const float*)d_in[17];
    const float* fc2b  = (const float*)d_in[18];
    const float* fc3w  = (const float*)d_in[19];
    const float* fc3b  = (const float*)d_in[20];

    float* P  = (float*)d_ws;
    float* FA = P + OFF_FEATS_A;
    float* FB = P + OFF_FEATS_B;

    prep_kernel<<<64, 256, 0, stream>>>(Wih0, Whh0, bih0, bhh0, Wih1, Whh1, bih1, bhh1,
                                        fc1w, fc1b, convw, convb, fc2w, fc2b, fc3w, fc3b,
                                        gparam, eattr, P);
    lstm_fc1_kernel<<<2048, 256, 0, stream>>>(x, P, FA);
    conv_fused_kernel<<<512, 256, 0, stream>>>(FA, FB, P, 0);
    conv_fused_kernel<<<512, 256, 0, stream>>>(FB, FA, P, 1);
    conv_fused_kernel<<<512, 256, 0, stream>>>(FA, FB, P, 2);
    conv_head_kernel<<<512, 256, 0, stream>>>(FB, P, (float*)d_out);
}